// Round 2
// baseline (692.203 us; speedup 1.0000x reference)
//
#include <hip/hip_runtime.h>

typedef unsigned short u16;
typedef unsigned int u32;
typedef __bf16 bf16x8 __attribute__((ext_vector_type(8)));
typedef float f32x4 __attribute__((ext_vector_type(4)));
typedef u16 u16x8 __attribute__((ext_vector_type(8)));

#define DEV static __device__ __forceinline__

// B=2, T=2048, C=1024, H=16, D=64, DEPTH=3
#define TT 2048
#define CC 1024
#define HH 16
#define DD 64

DEV u16 f2bf(float f) {
    u32 u = __float_as_uint(f);
    u += 0x7fffu + ((u >> 16) & 1u);
    return (u16)(u >> 16);
}

DEV void gload_lds16(const void* g, void* l) {
    __builtin_amdgcn_global_load_lds(
        (const __attribute__((address_space(1))) void*)g,
        (__attribute__((address_space(3))) void*)l,
        16, 0, 0);
}

// ---------------- converts ----------------
__global__ __launch_bounds__(256) void cvt_x(const float* __restrict__ x,
                                             u16* __restrict__ xb, int n4) {
    int i = blockIdx.x * 256 + threadIdx.x;
    if (i < n4) {
        float4 v = ((const float4*)x)[i];
        u16 o0 = f2bf(v.x), o1 = f2bf(v.y), o2 = f2bf(v.z), o3 = f2bf(v.w);
        u32 lo = (u32)o0 | ((u32)o1 << 16);
        u32 hi = (u32)o2 | ((u32)o3 << 16);
        ((u32*)xb)[i * 2]     = lo;
        ((u32*)xb)[i * 2 + 1] = hi;
    }
}

// W [K][N] fp32 -> Wt [N][K] bf16
__global__ __launch_bounds__(256) void cvt_w_t(const float* __restrict__ W,
                                               u16* __restrict__ Wt, int K, int N) {
    __shared__ float tile[32][33];
    int n0 = blockIdx.x * 32, k0 = blockIdx.y * 32;
    int tx = threadIdx.x & 31, ty = threadIdx.x >> 5;  // 32 x 8
#pragma unroll
    for (int i = 0; i < 4; i++)
        tile[ty + i * 8][tx] = W[(size_t)(k0 + ty + i * 8) * N + n0 + tx];
    __syncthreads();
#pragma unroll
    for (int i = 0; i < 4; i++) {
        int rr = ty + i * 8;
        Wt[(size_t)(n0 + rr) * K + k0 + tx] = f2bf(tile[tx][rr]);
    }
}

// ---------------- GEMM: C[M,N] = A[M,K](bf16) * Bt[N,K]^T(bf16) + bias ----------------
// 128x128 tile, BK=32, 4 waves, each wave 64x64 (4x4 frags of 16x16x32 MFMA)
template <int OUTF>
__global__ __launch_bounds__(256) void gemm_bf16(const u16* __restrict__ A,
                                                 const u16* __restrict__ Bt,
                                                 const float* __restrict__ bias,
                                                 void* __restrict__ Cout,
                                                 int K, int ldc) {
    __shared__ __align__(16) u16 As[4096];  // [128][32]
    __shared__ __align__(16) u16 Bs[4096];  // [128][32]

    const int tid = threadIdx.x;
    const int w = tid >> 6, l = tid & 63;
    const int wr = w >> 1, wc = w & 1;
    const int c = l & 15, g = l >> 4;
    const int rowB = blockIdx.y * 128;
    const int colB = blockIdx.x * 128;
    const int sr = l >> 2;          // staging row-in-quarter
    const int sk = (l & 3) * 8;     // staging k elem offset

    const f32x4 fz = {0.f, 0.f, 0.f, 0.f};
    f32x4 acc[4][4];
#pragma unroll
    for (int m = 0; m < 4; m++)
#pragma unroll
        for (int n = 0; n < 4; n++) acc[m][n] = fz;

    for (int k0 = 0; k0 < K; k0 += 32) {
#pragma unroll
        for (int i = 0; i < 2; i++) {
            int r = i * 64 + w * 16 + sr;
            gload_lds16(A + (size_t)(rowB + r) * K + k0 + sk, &As[i * 2048 + w * 512]);
            gload_lds16(Bt + (size_t)(colB + r) * K + k0 + sk, &Bs[i * 2048 + w * 512]);
        }
        asm volatile("s_waitcnt vmcnt(0)" ::: "memory");
        __syncthreads();

        bf16x8 af[4], bfr[4];
#pragma unroll
        for (int m = 0; m < 4; m++)
            af[m] = *(const bf16x8*)&As[(wr * 64 + m * 16 + c) * 32 + g * 8];
#pragma unroll
        for (int n = 0; n < 4; n++)
            bfr[n] = *(const bf16x8*)&Bs[(wc * 64 + n * 16 + c) * 32 + g * 8];
#pragma unroll
        for (int m = 0; m < 4; m++)
#pragma unroll
            for (int n = 0; n < 4; n++)
                acc[m][n] = __builtin_amdgcn_mfma_f32_16x16x32_bf16(af[m], bfr[n], acc[m][n], 0, 0, 0);
        __syncthreads();
    }

    const int orow = rowB + wr * 64;
    const int ocol = colB + wc * 64;
#pragma unroll
    for (int m = 0; m < 4; m++)
#pragma unroll
        for (int n = 0; n < 4; n++) {
            int col = ocol + n * 16 + c;
            float bv = bias[col];
#pragma unroll
            for (int j = 0; j < 4; j++) {
                int row = orow + m * 16 + g * 4 + j;
                float v = acc[m][n][j] + bv;
                if (OUTF)
                    ((float*)Cout)[(size_t)row * ldc + col] = v;
                else
                    ((u16*)Cout)[(size_t)row * ldc + col] = f2bf(v);
            }
        }
}

// ---------------- flash causal attention, one depth ----------------
// grid: (T/128, B*H). 4 waves/block, wave owns 32 q rows. KV tiles of 64.
__global__ __launch_bounds__(256) void attn_kernel(const u16* __restrict__ QKV,  // [B*T][3C]
                                                   const float* __restrict__ gates,
                                                   float* __restrict__ attF,  // [B*T][C] fp32 state (= d_out)
                                                   u16* __restrict__ attB,    // [B*T][C] bf16 copy
                                                   int depth) {
    __shared__ __align__(16) u16 Ks[4096];  // [ds=2][kv=64][d'=32]
    __shared__ __align__(16) u16 Vs[4096];  // [ks=2][d=64][kv'=32]  (V transposed)
    __shared__ __align__(16) u16 Ps[8192];  // per wave 2048: [ks=2][q=32][kv'=32]

    const int tid = threadIdx.x;
    const int w = tid >> 6, l = tid & 63;
    const int c = l & 15, g = l >> 4;
    const int bh = blockIdx.y;
    const int b = bh >> 4, h = bh & 15;
    const int qb = blockIdx.x * 128;
    const size_t rowbase = (size_t)b * TT;
    const int myrow_min = qb + w * 32;
    const f32x4 fz = {0.f, 0.f, 0.f, 0.f};

    // Q fragments stay in registers for whole kernel
    bf16x8 qa[2][2];
#pragma unroll
    for (int rb = 0; rb < 2; rb++)
#pragma unroll
        for (int ds = 0; ds < 2; ds++) {
            int t = qb + w * 32 + rb * 16 + c;
            qa[rb][ds] = *(const bf16x8*)&QKV[(rowbase + t) * (3 * CC) + h * DD + ds * 32 + g * 8];
        }

    f32x4 O[2][4];
#pragma unroll
    for (int rb = 0; rb < 2; rb++)
#pragma unroll
        for (int nd = 0; nd < 4; nd++) O[rb][nd] = fz;
    float mrow[2][4], lrow[2][4];
#pragma unroll
    for (int rb = 0; rb < 2; rb++)
#pragma unroll
        for (int j = 0; j < 4; j++) { mrow[rb][j] = -1e30f; lrow[rb][j] = 0.f; }

    const int nkv = qb + 128;
    for (int kv0 = 0; kv0 < nkv; kv0 += 64) {
        // stage K via global_load_lds (linear [ds][kv][32] layout)
#pragma unroll
        for (int i = 0; i < 2; i++)
            gload_lds16(QKV + (rowbase + kv0 + w * 16 + (l >> 2)) * (3 * CC) + CC + h * DD + i * 32 + (l & 3) * 8,
                        &Ks[i * 2048 + w * 512]);
        // stage V transposed (reg route)
#pragma unroll
        for (int s = 0; s < 2; s++) {
            int kv = w * 16 + (l >> 2);
            int d0 = (l & 3) * 16 + s * 8;
            u16x8 v = *(const u16x8*)&QKV[(rowbase + kv0 + kv) * (3 * CC) + 2 * CC + h * DD + d0];
            int base = ((kv >> 5) << 11) + (kv & 31);
#pragma unroll
            for (int ii = 0; ii < 8; ii++) Vs[base + (d0 + ii) * 32] = v[ii];
        }
        asm volatile("s_waitcnt vmcnt(0)" ::: "memory");
        __syncthreads();

        if (kv0 <= myrow_min + 31) {  // wave has >=1 unmasked column in this tile
            f32x4 s[2][4];
#pragma unroll
            for (int rb = 0; rb < 2; rb++)
#pragma unroll
                for (int n = 0; n < 4; n++) s[rb][n] = fz;
            // S = Q K^T
#pragma unroll
            for (int ds = 0; ds < 2; ds++)
#pragma unroll
                for (int n = 0; n < 4; n++) {
                    bf16x8 kb = *(const bf16x8*)&Ks[ds * 2048 + (n * 16 + c) * 32 + g * 8];
#pragma unroll
                    for (int rb = 0; rb < 2; rb++)
                        s[rb][n] = __builtin_amdgcn_mfma_f32_16x16x32_bf16(qa[rb][ds], kb, s[rb][n], 0, 0, 0);
                }

            const bool needmask = (kv0 + 63 > myrow_min);
#pragma unroll
            for (int rb = 0; rb < 2; rb++) {
#pragma unroll
                for (int n = 0; n < 4; n++)
#pragma unroll
                    for (int j = 0; j < 4; j++) {
                        float v = s[rb][n][j] * 0.125f;
                        if (needmask) {
                            int row = myrow_min + rb * 16 + g * 4 + j;
                            int col = kv0 + n * 16 + c;
                            if (col > row) v = -1e30f;
                        }
                        s[rb][n][j] = v;
                    }
#pragma unroll
                for (int j = 0; j < 4; j++) {
                    float m0 = fmaxf(fmaxf(s[rb][0][j], s[rb][1][j]), fmaxf(s[rb][2][j], s[rb][3][j]));
#pragma unroll
                    for (int off = 1; off < 16; off <<= 1)
                        m0 = fmaxf(m0, __shfl_xor(m0, off, 64));
                    float mn = fmaxf(mrow[rb][j], m0);
                    float esc = __expf(mrow[rb][j] - mn);
                    mrow[rb][j] = mn;
#pragma unroll
                    for (int nd = 0; nd < 4; nd++) O[rb][nd][j] *= esc;
                    float rsum = 0.f;
#pragma unroll
                    for (int n = 0; n < 4; n++) {
                        float p = __expf(s[rb][n][j] - mn);
                        s[rb][n][j] = p;
                        rsum += p;
                    }
#pragma unroll
                    for (int off = 1; off < 16; off <<= 1)
                        rsum += __shfl_xor(rsum, off, 64);
                    lrow[rb][j] = lrow[rb][j] * esc + rsum;
                }
                // write P (bf16) to per-wave LDS in [ks][q][kv'] layout
#pragma unroll
                for (int n = 0; n < 4; n++)
#pragma unroll
                    for (int j = 0; j < 4; j++)
                        Ps[w * 2048 + (n >> 1) * 1024 + (rb * 16 + g * 4 + j) * 32 + (n & 1) * 16 + c] =
                            f2bf(s[rb][n][j]);
            }
            asm volatile("s_waitcnt lgkmcnt(0)" ::: "memory");
            // O += P V
#pragma unroll
            for (int ks = 0; ks < 2; ks++) {
                bf16x8 pa[2];
#pragma unroll
                for (int rb = 0; rb < 2; rb++)
                    pa[rb] = *(const bf16x8*)&Ps[w * 2048 + ks * 1024 + (rb * 16 + c) * 32 + g * 8];
#pragma unroll
                for (int nd = 0; nd < 4; nd++) {
                    bf16x8 vb = *(const bf16x8*)&Vs[ks * 2048 + (nd * 16 + c) * 32 + g * 8];
#pragma unroll
                    for (int rb = 0; rb < 2; rb++)
                        O[rb][nd] = __builtin_amdgcn_mfma_f32_16x16x32_bf16(pa[rb], vb, O[rb][nd], 0, 0, 0);
                }
            }
        }
        __syncthreads();
    }

    // epilogue: normalize, gate, write fp32 state + bf16 copy
    float gv = gates[depth];
    float sg = 1.f / (1.f + __expf(-gv));
#pragma unroll
    for (int rb = 0; rb < 2; rb++) {
        float inv[4];
#pragma unroll
        for (int j = 0; j < 4; j++) inv[j] = 1.f / lrow[rb][j];
#pragma unroll
        for (int nd = 0; nd < 4; nd++)
#pragma unroll
            for (int j = 0; j < 4; j++) {
                float cur = O[rb][nd][j] * inv[j];
                size_t idx = (rowbase + qb + w * 32 + rb * 16 + g * 4 + j) * CC + h * DD + nd * 16 + c;
                float res;
                if (depth == 0) res = cur;
                else res = sg * cur + (1.f - sg) * attF[idx];
                if (depth < 2) attF[idx] = res;  // depth-2 fp32 state is dead (final GEMM reads attB)
                attB[idx] = f2bf(res);
            }
    }
}

// ---------------- host ----------------
extern "C" void kernel_launch(void* const* d_in, const int* in_sizes, int n_in,
                              void* d_out, int out_size, void* d_ws, size_t ws_size,
                              hipStream_t stream) {
    const float* x      = (const float*)d_in[0];
    const float* W_attn = (const float*)d_in[1];
    const float* b_attn = (const float*)d_in[2];
    const float* W_proj = (const float*)d_in[3];
    const float* b_proj = (const float*)d_in[4];
    const float* gates  = (const float*)d_in[5];
    float* out = (float*)d_out;

    // ws layout (40 MiB total):
    //   [0,8M)    Xb   [4096][1024] bf16  -- dead after QKV GEMM; reused as attB
    //   [8M,14M)  Wta  [3072][1024] bf16  (W_attn^T)
    //   [14M,16M) Wtp  [1024][1024] bf16  (W_proj^T)
    //   [16M,40M) QKV  [4096][3072] bf16
    // attF (fp32 gating state) aliases d_out: fully overwritten by final GEMM,
    // never read before written (depth0 writes, depth1/2 read).
    char* ws = (char*)d_ws;
    u16*   Xb   = (u16*)(ws);
    u16*   attB = (u16*)(ws);               // alias of Xb (Xb dead by then)
    u16*   Wta  = (u16*)(ws + 8388608);
    u16*   Wtp  = (u16*)(ws + 14680064);
    u16*   QKV  = (u16*)(ws + 16777216);
    float* attF = out;                      // alias of d_out
    (void)ws_size; (void)in_sizes; (void)n_in; (void)out_size;

    cvt_x<<<4096, 256, 0, stream>>>(x, Xb, 1048576);
    cvt_w_t<<<dim3(96, 32), 256, 0, stream>>>(W_attn, Wta, 1024, 3072);
    cvt_w_t<<<dim3(32, 32), 256, 0, stream>>>(W_proj, Wtp, 1024, 1024);

    // QKV projection: [4096,1024] x [1024,3072] -> bf16 [4096][3072]
    gemm_bf16<0><<<dim3(24, 32), 256, 0, stream>>>(Xb, Wta, b_attn, QKV, 1024, 3072);

    for (int depth = 0; depth < 3; depth++) {
        attn_kernel<<<dim3(16, 32), 256, 0, stream>>>(QKV, gates, attF, attB, depth);
        if (depth < 2) {
            // refinement: att_bf16 x W_attn[:, :2048]^T -> new q,k into QKV cols [0,2048)
            gemm_bf16<0><<<dim3(16, 32), 256, 0, stream>>>(attB, Wta, b_attn, QKV, 1024, 3072);
        }
    }
    // output projection -> fp32 d_out
    gemm_bf16<1><<<dim3(8, 32), 256, 0, stream>>>(attB, Wtp, b_proj, out, 1024, 1024);
}

// Round 4
// 509.557 us; speedup vs baseline: 1.3584x; 1.3584x over previous
//
#include <hip/hip_runtime.h>

typedef unsigned short u16;
typedef unsigned int u32;
typedef __bf16 bf16x8 __attribute__((ext_vector_type(8)));
typedef float f32x4 __attribute__((ext_vector_type(4)));
typedef u16 u16x8 __attribute__((ext_vector_type(8)));

#define DEV static __device__ __forceinline__

// B=2, T=2048, C=1024, H=16, D=64, DEPTH=3
#define TT 2048
#define CC 1024
#define HH 16
#define DD 64

DEV u16 f2bf(float f) {
    u32 u = __float_as_uint(f);
    u += 0x7fffu + ((u >> 16) & 1u);
    return (u16)(u >> 16);
}

DEV void gload_lds16(const void* g, void* l) {
    __builtin_amdgcn_global_load_lds(
        (const __attribute__((address_space(1))) void*)g,
        (__attribute__((address_space(3))) void*)l,
        16, 0, 0);
}

// ---------------- converts ----------------
__global__ __launch_bounds__(256) void cvt_x(const float* __restrict__ x,
                                             u16* __restrict__ xb, int n4) {
    int i = blockIdx.x * 256 + threadIdx.x;
    if (i < n4) {
        float4 v = ((const float4*)x)[i];
        u16 o0 = f2bf(v.x), o1 = f2bf(v.y), o2 = f2bf(v.z), o3 = f2bf(v.w);
        u32 lo = (u32)o0 | ((u32)o1 << 16);
        u32 hi = (u32)o2 | ((u32)o3 << 16);
        ((u32*)xb)[i * 2]     = lo;
        ((u32*)xb)[i * 2 + 1] = hi;
    }
}

// W [K][N] fp32 -> Wt [N][K] bf16
__global__ __launch_bounds__(256) void cvt_w_t(const float* __restrict__ W,
                                               u16* __restrict__ Wt, int K, int N) {
    __shared__ float tile[32][33];
    int n0 = blockIdx.x * 32, k0 = blockIdx.y * 32;
    int tx = threadIdx.x & 31, ty = threadIdx.x >> 5;  // 32 x 8
#pragma unroll
    for (int i = 0; i < 4; i++)
        tile[ty + i * 8][tx] = W[(size_t)(k0 + ty + i * 8) * N + n0 + tx];
    __syncthreads();
#pragma unroll
    for (int i = 0; i < 4; i++) {
        int rr = ty + i * 8;
        Wt[(size_t)(n0 + rr) * K + k0 + tx] = f2bf(tile[tx][rr]);
    }
}

// ---------------- GEMM: C[M,N] = A[M,K](bf16) * Bt[N,K]^T(bf16) + bias ----------------
// 128x128 tile, BK=32, 4 waves, each wave 64x64 (4x4 frags of 16x16x32 MFMA)
template <int OUTF>
__global__ __launch_bounds__(256) void gemm_bf16(const u16* __restrict__ A,
                                                 const u16* __restrict__ Bt,
                                                 const float* __restrict__ bias,
                                                 void* __restrict__ Cout,
                                                 int K, int ldc) {
    __shared__ __align__(16) u16 As[4096];  // [128][32]
    __shared__ __align__(16) u16 Bs[4096];  // [128][32]

    const int tid = threadIdx.x;
    const int w = tid >> 6, l = tid & 63;
    const int wr = w >> 1, wc = w & 1;
    const int c = l & 15, g = l >> 4;
    const int rowB = blockIdx.y * 128;
    const int colB = blockIdx.x * 128;
    const int sr = l >> 2;          // staging row-in-quarter
    const int sk = (l & 3) * 8;     // staging k elem offset

    const f32x4 fz = {0.f, 0.f, 0.f, 0.f};
    f32x4 acc[4][4];
#pragma unroll
    for (int m = 0; m < 4; m++)
#pragma unroll
        for (int n = 0; n < 4; n++) acc[m][n] = fz;

    for (int k0 = 0; k0 < K; k0 += 32) {
#pragma unroll
        for (int i = 0; i < 2; i++) {
            int r = i * 64 + w * 16 + sr;
            gload_lds16(A + (size_t)(rowB + r) * K + k0 + sk, &As[i * 2048 + w * 512]);
            gload_lds16(Bt + (size_t)(colB + r) * K + k0 + sk, &Bs[i * 2048 + w * 512]);
        }
        asm volatile("s_waitcnt vmcnt(0)" ::: "memory");
        __syncthreads();

        bf16x8 af[4], bfr[4];
#pragma unroll
        for (int m = 0; m < 4; m++)
            af[m] = *(const bf16x8*)&As[(wr * 64 + m * 16 + c) * 32 + g * 8];
#pragma unroll
        for (int n = 0; n < 4; n++)
            bfr[n] = *(const bf16x8*)&Bs[(wc * 64 + n * 16 + c) * 32 + g * 8];
#pragma unroll
        for (int m = 0; m < 4; m++)
#pragma unroll
            for (int n = 0; n < 4; n++)
                acc[m][n] = __builtin_amdgcn_mfma_f32_16x16x32_bf16(af[m], bfr[n], acc[m][n], 0, 0, 0);
        __syncthreads();
    }

    const int orow = rowB + wr * 64;
    const int ocol = colB + wc * 64;
#pragma unroll
    for (int m = 0; m < 4; m++)
#pragma unroll
        for (int n = 0; n < 4; n++) {
            int col = ocol + n * 16 + c;
            float bv = bias[col];
#pragma unroll
            for (int j = 0; j < 4; j++) {
                int row = orow + m * 16 + g * 4 + j;
                float v = acc[m][n][j] + bv;
                if (OUTF)
                    ((float*)Cout)[(size_t)row * ldc + col] = v;
                else
                    ((u16*)Cout)[(size_t)row * ldc + col] = f2bf(v);
            }
        }
}

// ---------------- flash causal attention, one depth ----------------
// grid: (32, 32) remapped. 4 waves/block, wave owns 16 q rows (QBLK=64). KV tiles of 64.
// LDS layouts (all XOR-swizzled, 128B rows):
//   Ks: K(kv,d)  at u16 idx  kv*64 + ((d)        ^ ((kv&7)<<3))   [staged via gload_lds, pre-swizzled src]
//   Vs: V(kv,d)  at u16 idx  d*64  + ((kv)       ^ ((d&7)<<3))    [transposed via registers]
//   Ps: P(q,kv)  at u16 idx  w*1024 + q*64 + (kv ^ ((q&7)<<3))    [per-wave]
__global__ __launch_bounds__(256) void attn_kernel(const u16* __restrict__ QKV,  // [B*T][3C]
                                                   const float* __restrict__ gates,
                                                   float* __restrict__ attF,  // [B*T][C] fp32 state (= d_out)
                                                   u16* __restrict__ attB,    // [B*T][C] bf16 copy
                                                   int depth) {
    __shared__ __align__(16) u16 Ks[4096];  // 8KB
    __shared__ __align__(16) u16 Vs[4096];  // 8KB
    __shared__ __align__(16) u16 Ps[4096];  // 8KB (4 waves x 2KB)

    const int tid = threadIdx.x;
    const int w = tid >> 6, l = tid & 63;
    const int c = l & 15, g = l >> 4;

    // XCD-aware bijective remap (each XCD owns 4 bh values) + heavy-first qb order
    const int f = blockIdx.y * 32 + blockIdx.x;   // dispatch-linear id
    const int xcd = f & 7;
    const int idx = f >> 3;                        // 0..127
    const int bh = xcd + 8 * (idx >> 5);           // 0..31
    const int qbI = 31 - (idx & 31);               // heavy blocks first
    const int b = bh >> 4, h = bh & 15;
    const int qb = qbI * 64;
    const size_t rowbase = (size_t)b * TT;
    const int qrow0 = qb + w * 16;                 // wave's 16 q rows
    const f32x4 fz = {0.f, 0.f, 0.f, 0.f};

    // Q fragments in registers for whole kernel (A-frag: row=c, k=ds*32+g*8+i)
    bf16x8 qa[2];
#pragma unroll
    for (int ds = 0; ds < 2; ds++)
        qa[ds] = *(const bf16x8*)&QKV[(rowbase + qrow0 + c) * (3 * CC) + h * DD + ds * 32 + g * 8];

    f32x4 O[4];
#pragma unroll
    for (int nd = 0; nd < 4; nd++) O[nd] = fz;
    float mrow[4], lrow[4];
#pragma unroll
    for (int j = 0; j < 4; j++) { mrow[j] = -1e30f; lrow[j] = 0.f; }

    const int ntiles = qbI + 1;
    for (int t = 0; t < ntiles; t++) {
        const int kv0 = t * 64;
        // ---- stage V via registers (transposed, conflict-free writes) ----
        // lane l covers kv=l; wave w covers d rows [w*8+r*32, +8)
        u16x8 vv[2];
#pragma unroll
        for (int r = 0; r < 2; r++) {
            int d0 = w * 8 + r * 32;
            vv[r] = *(const u16x8*)&QKV[(rowbase + kv0 + l) * (3 * CC) + 2 * CC + h * DD + d0];
        }
        // ---- stage K via gload_lds, pre-swizzled global source ----
#pragma unroll
        for (int r = 0; r < 2; r++) {
            int row = w * 8 + r * 32 + (l >> 3);   // dest LDS row for this lane
            int srccolb = (((l & 7) ^ (l >> 3)) << 4);  // swizzled d-byte offset
            const char* src = (const char*)(QKV + (rowbase + kv0 + row) * (3 * CC) + CC + h * DD) + srccolb;
            gload_lds16(src, &Ks[r * 2048 + w * 512]);
        }
        // V transposed writes (bank = (l>>1)^const -> 2-way, free)
#pragma unroll
        for (int r = 0; r < 2; r++) {
            int d0 = w * 8 + r * 32;
#pragma unroll
            for (int ii = 0; ii < 8; ii++)
                Vs[(d0 + ii) * 64 + (l ^ (ii << 3))] = vv[r][ii];
        }
        asm volatile("s_waitcnt vmcnt(0)" ::: "memory");
        __syncthreads();

        if (kv0 <= qrow0 + 15) {  // wave participates in this tile
            f32x4 s[4];
#pragma unroll
            for (int n = 0; n < 4; n++) s[n] = fz;
            // ---- S = Q K^T ----
#pragma unroll
            for (int ds = 0; ds < 2; ds++)
#pragma unroll
                for (int n = 0; n < 4; n++) {
                    bf16x8 kb = *(const bf16x8*)&Ks[(n * 16 + c) * 64 + ((ds * 32 + g * 8) ^ ((c & 7) << 3))];
                    s[n] = __builtin_amdgcn_mfma_f32_16x16x32_bf16(qa[ds], kb, s[n], 0, 0, 0);
                }

            const bool needmask = (kv0 + 63 > qrow0);
#pragma unroll
            for (int n = 0; n < 4; n++)
#pragma unroll
                for (int j = 0; j < 4; j++) {
                    float v = s[n][j] * 0.125f;
                    if (needmask) {
                        int row = qrow0 + g * 4 + j;
                        int col = kv0 + n * 16 + c;
                        if (col > row) v = -1e30f;
                    }
                    s[n][j] = v;
                }
            // ---- online softmax (per row j, 16-lane-group reductions) ----
#pragma unroll
            for (int j = 0; j < 4; j++) {
                float m0 = fmaxf(fmaxf(s[0][j], s[1][j]), fmaxf(s[2][j], s[3][j]));
#pragma unroll
                for (int off = 1; off < 16; off <<= 1)
                    m0 = fmaxf(m0, __shfl_xor(m0, off, 64));
                float mn = fmaxf(mrow[j], m0);
                float esc = __expf(mrow[j] - mn);
                mrow[j] = mn;
#pragma unroll
                for (int nd = 0; nd < 4; nd++) O[nd][j] *= esc;
                float rsum = 0.f;
#pragma unroll
                for (int n = 0; n < 4; n++) {
                    float p = __expf(s[n][j] - mn);
                    s[n][j] = p;
                    rsum += p;
                }
#pragma unroll
                for (int off = 1; off < 16; off <<= 1)
                    rsum += __shfl_xor(rsum, off, 64);
                lrow[j] = lrow[j] * esc + rsum;
            }
            // ---- write P to per-wave swizzled LDS ----
#pragma unroll
            for (int n = 0; n < 4; n++)
#pragma unroll
                for (int j = 0; j < 4; j++) {
                    int q = g * 4 + j;
                    Ps[w * 1024 + q * 64 + ((n * 16 + c) ^ ((q & 7) << 3))] = f2bf(s[n][j]);
                }
            asm volatile("s_waitcnt lgkmcnt(0)" ::: "memory");
            // ---- O += P V ----
#pragma unroll
            for (int ks = 0; ks < 2; ks++) {
                bf16x8 pa = *(const bf16x8*)&Ps[w * 1024 + c * 64 + ((ks * 32 + g * 8) ^ ((c & 7) << 3))];
#pragma unroll
                for (int nd = 0; nd < 4; nd++) {
                    bf16x8 vb = *(const bf16x8*)&Vs[(nd * 16 + c) * 64 + ((ks * 32 + g * 8) ^ ((c & 7) << 3))];
                    O[nd] = __builtin_amdgcn_mfma_f32_16x16x32_bf16(pa, vb, O[nd], 0, 0, 0);
                }
            }
        }
        __syncthreads();
    }

    // ---- epilogue: normalize, gate, write fp32 state + bf16 copy ----
    float gv = gates[depth];
    float sg = 1.f / (1.f + __expf(-gv));
    float inv[4];
#pragma unroll
    for (int j = 0; j < 4; j++) inv[j] = 1.f / lrow[j];
#pragma unroll
    for (int nd = 0; nd < 4; nd++)
#pragma unroll
        for (int j = 0; j < 4; j++) {
            float cur = O[nd][j] * inv[j];
            size_t idxo = (rowbase + qrow0 + g * 4 + j) * CC + h * DD + nd * 16 + c;
            float res;
            if (depth == 0) res = cur;
            else res = sg * cur + (1.f - sg) * attF[idxo];
            if (depth < 2) attF[idxo] = res;  // depth-2 fp32 state is dead (final GEMM reads attB)
            attB[idxo] = f2bf(res);
        }
}

// ---------------- host ----------------
extern "C" void kernel_launch(void* const* d_in, const int* in_sizes, int n_in,
                              void* d_out, int out_size, void* d_ws, size_t ws_size,
                              hipStream_t stream) {
    const float* x      = (const float*)d_in[0];
    const float* W_attn = (const float*)d_in[1];
    const float* b_attn = (const float*)d_in[2];
    const float* W_proj = (const float*)d_in[3];
    const float* b_proj = (const float*)d_in[4];
    const float* gates  = (const float*)d_in[5];
    float* out = (float*)d_out;

    // ws layout (40 MiB):
    //   [0,8M)    Xb   [4096][1024] bf16  -- dead after QKV GEMM; reused as attB
    //   [8M,14M)  Wta  [3072][1024] bf16  (W_attn^T)
    //   [14M,16M) Wtp  [1024][1024] bf16  (W_proj^T)
    //   [16M,40M) QKV  [4096][3072] bf16
    // attF (fp32 gating state) aliases d_out (overwritten by final GEMM; never read-before-write).
    char* ws = (char*)d_ws;
    u16*   Xb   = (u16*)(ws);
    u16*   attB = (u16*)(ws);               // alias of Xb (Xb dead by then)
    u16*   Wta  = (u16*)(ws + 8388608);
    u16*   Wtp  = (u16*)(ws + 14680064);
    u16*   QKV  = (u16*)(ws + 16777216);
    float* attF = out;                      // alias of d_out
    (void)ws_size; (void)in_sizes; (void)n_in; (void)out_size;

    cvt_x<<<4096, 256, 0, stream>>>(x, Xb, 1048576);
    cvt_w_t<<<dim3(96, 32), 256, 0, stream>>>(W_attn, Wta, 1024, 3072);
    cvt_w_t<<<dim3(32, 32), 256, 0, stream>>>(W_proj, Wtp, 1024, 1024);

    // QKV projection: [4096,1024] x [1024,3072] -> bf16 [4096][3072]
    gemm_bf16<0><<<dim3(24, 32), 256, 0, stream>>>(Xb, Wta, b_attn, QKV, 1024, 3072);

    for (int depth = 0; depth < 3; depth++) {
        attn_kernel<<<dim3(32, 32), 256, 0, stream>>>(QKV, gates, attF, attB, depth);
        if (depth < 2) {
            // refinement: att_bf16 x W_attn[:, :2048]^T -> new q,k into QKV cols [0,2048)
            gemm_bf16<0><<<dim3(16, 32), 256, 0, stream>>>(attB, Wta, b_attn, QKV, 1024, 3072);
        }
    }
    // output projection -> fp32 d_out
    gemm_bf16<1><<<dim3(8, 32), 256, 0, stream>>>(attB, Wtp, b_proj, out, 1024, 1024);
}

// Round 5
// 503.914 us; speedup vs baseline: 1.3737x; 1.0112x over previous
//
#include <hip/hip_runtime.h>

typedef unsigned short u16;
typedef unsigned int u32;
typedef __bf16 bf16x8 __attribute__((ext_vector_type(8)));
typedef float f32x4 __attribute__((ext_vector_type(4)));
typedef u16 u16x8 __attribute__((ext_vector_type(8)));

#define DEV static __device__ __forceinline__

// B=2, T=2048, C=1024, H=16, D=64, DEPTH=3
#define TT 2048
#define CC 1024
#define HH 16
#define DD 64

DEV u16 f2bf(float f) {
    u32 u = __float_as_uint(f);
    u += 0x7fffu + ((u >> 16) & 1u);
    return (u16)(u >> 16);
}

DEV void gload_lds16(const void* g, void* l) {
    __builtin_amdgcn_global_load_lds(
        (const __attribute__((address_space(1))) void*)g,
        (__attribute__((address_space(3))) void*)l,
        16, 0, 0);
}

// ---------------- converts ----------------
__global__ __launch_bounds__(256) void cvt_x(const float* __restrict__ x,
                                             u16* __restrict__ xb, int n4) {
    int i = blockIdx.x * 256 + threadIdx.x;
    if (i < n4) {
        float4 v = ((const float4*)x)[i];
        u16 o0 = f2bf(v.x), o1 = f2bf(v.y), o2 = f2bf(v.z), o3 = f2bf(v.w);
        u32 lo = (u32)o0 | ((u32)o1 << 16);
        u32 hi = (u32)o2 | ((u32)o3 << 16);
        ((u32*)xb)[i * 2]     = lo;
        ((u32*)xb)[i * 2 + 1] = hi;
    }
}

// W [K][N] fp32 -> Wt [N][K] bf16
__global__ __launch_bounds__(256) void cvt_w_t(const float* __restrict__ W,
                                               u16* __restrict__ Wt, int K, int N) {
    __shared__ float tile[32][33];
    int n0 = blockIdx.x * 32, k0 = blockIdx.y * 32;
    int tx = threadIdx.x & 31, ty = threadIdx.x >> 5;  // 32 x 8
#pragma unroll
    for (int i = 0; i < 4; i++)
        tile[ty + i * 8][tx] = W[(size_t)(k0 + ty + i * 8) * N + n0 + tx];
    __syncthreads();
#pragma unroll
    for (int i = 0; i < 4; i++) {
        int rr = ty + i * 8;
        Wt[(size_t)(n0 + rr) * K + k0 + tx] = f2bf(tile[tx][rr]);
    }
}

// ---------------- GEMM: C[M,N] = A[M,K](bf16) * Bt[N,K]^T(bf16) + bias ----------------
// 128x128 tile, BK=32, 4 waves, each wave 64x64 (4x4 frags of 16x16x32 MFMA)
template <int OUTF>
__global__ __launch_bounds__(256) void gemm_bf16(const u16* __restrict__ A,
                                                 const u16* __restrict__ Bt,
                                                 const float* __restrict__ bias,
                                                 void* __restrict__ Cout,
                                                 int K, int ldc) {
    __shared__ __align__(16) u16 As[4096];  // [128][32]
    __shared__ __align__(16) u16 Bs[4096];  // [128][32]

    const int tid = threadIdx.x;
    const int w = tid >> 6, l = tid & 63;
    const int wr = w >> 1, wc = w & 1;
    const int c = l & 15, g = l >> 4;
    const int rowB = blockIdx.y * 128;
    const int colB = blockIdx.x * 128;
    const int sr = l >> 2;          // staging row-in-quarter
    const int sk = (l & 3) * 8;     // staging k elem offset

    const f32x4 fz = {0.f, 0.f, 0.f, 0.f};
    f32x4 acc[4][4];
#pragma unroll
    for (int m = 0; m < 4; m++)
#pragma unroll
        for (int n = 0; n < 4; n++) acc[m][n] = fz;

    for (int k0 = 0; k0 < K; k0 += 32) {
#pragma unroll
        for (int i = 0; i < 2; i++) {
            int r = i * 64 + w * 16 + sr;
            gload_lds16(A + (size_t)(rowB + r) * K + k0 + sk, &As[i * 2048 + w * 512]);
            gload_lds16(Bt + (size_t)(colB + r) * K + k0 + sk, &Bs[i * 2048 + w * 512]);
        }
        asm volatile("s_waitcnt vmcnt(0)" ::: "memory");
        __syncthreads();

        bf16x8 af[4], bfr[4];
#pragma unroll
        for (int m = 0; m < 4; m++)
            af[m] = *(const bf16x8*)&As[(wr * 64 + m * 16 + c) * 32 + g * 8];
#pragma unroll
        for (int n = 0; n < 4; n++)
            bfr[n] = *(const bf16x8*)&Bs[(wc * 64 + n * 16 + c) * 32 + g * 8];
#pragma unroll
        for (int m = 0; m < 4; m++)
#pragma unroll
            for (int n = 0; n < 4; n++)
                acc[m][n] = __builtin_amdgcn_mfma_f32_16x16x32_bf16(af[m], bfr[n], acc[m][n], 0, 0, 0);
        __syncthreads();
    }

    const int orow = rowB + wr * 64;
    const int ocol = colB + wc * 64;
#pragma unroll
    for (int m = 0; m < 4; m++)
#pragma unroll
        for (int n = 0; n < 4; n++) {
            int col = ocol + n * 16 + c;
            float bv = bias[col];
#pragma unroll
            for (int j = 0; j < 4; j++) {
                int row = orow + m * 16 + g * 4 + j;
                float v = acc[m][n][j] + bv;
                if (OUTF)
                    ((float*)Cout)[(size_t)row * ldc + col] = v;
                else
                    ((u16*)Cout)[(size_t)row * ldc + col] = f2bf(v);
            }
        }
}

// ---------------- flash causal attention, one depth ----------------
// grid: (32, 32) remapped. 4 waves/block, wave owns 16 q rows (QBLK=64). KV tiles of 64.
// Double-buffered K/V (T3 2-phase + T14 async-STAGE split): issue tile t+1's
// K gload_lds + V reg loads BEFORE computing tile t; V ds_writes land after.
// LDS layouts (all XOR-swizzled, 128B rows):
//   Ks[bb]: K(kv,d)  at u16 idx  kv*64 + (d  ^ ((kv&7)<<3))   [gload_lds, pre-swizzled src]
//   Vs[bb]: V(kv,d)  at u16 idx  d*64  + (kv ^ ((d&7)<<3))    [transposed via registers]
//   Ps:     P(q,kv)  at u16 idx  w*1024 + q*64 + (kv ^ ((q&7)<<3))  [per-wave]
__global__ __launch_bounds__(256) void attn_kernel(const u16* __restrict__ QKV,  // [B*T][3C]
                                                   const float* __restrict__ gates,
                                                   float* __restrict__ attF,  // [B*T][C] fp32 state (= d_out)
                                                   u16* __restrict__ attB,    // [B*T][C] bf16 copy
                                                   int depth) {
    __shared__ __align__(16) u16 Ks[8192];  // 2 x 8KB
    __shared__ __align__(16) u16 Vs[8192];  // 2 x 8KB
    __shared__ __align__(16) u16 Ps[4096];  // 8KB (4 waves x 2KB)

    const int tid = threadIdx.x;
    const int w = tid >> 6, l = tid & 63;
    const int c = l & 15, g = l >> 4;

    // XCD-aware bijective remap (each XCD owns 4 bh values) + heavy-first qb order
    const int f = blockIdx.y * 32 + blockIdx.x;   // dispatch-linear id
    const int xcd = f & 7;
    const int idx = f >> 3;                        // 0..127
    const int bh = xcd + 8 * (idx >> 5);           // 0..31
    const int qbI = 31 - (idx & 31);               // heavy blocks first
    const int b = bh >> 4, h = bh & 15;
    const int qb = qbI * 64;
    const size_t rowbase = (size_t)b * TT;
    const int qrow0 = qb + w * 16;                 // wave's 16 q rows
    const f32x4 fz = {0.f, 0.f, 0.f, 0.f};

    // staging constants
    const int krow = l >> 3;                       // row-in-8-group
    const int kcolb = (((l & 7) ^ krow) << 4);     // pre-swizzled byte col

    // Q fragments in registers for whole kernel (A-frag: row=c, k=ds*32+g*8+i)
    bf16x8 qa[2];
#pragma unroll
    for (int ds = 0; ds < 2; ds++)
        qa[ds] = *(const bf16x8*)&QKV[(rowbase + qrow0 + c) * (3 * CC) + h * DD + ds * 32 + g * 8];

    f32x4 O[4];
#pragma unroll
    for (int nd = 0; nd < 4; nd++) O[nd] = fz;
    float mrow[4], lrow[4];
#pragma unroll
    for (int j = 0; j < 4; j++) { mrow[j] = -1e30f; lrow[j] = 0.f; }

    // ---- prologue: stage tile 0 into buffer 0 ----
    {
        u16x8 vv[2];
#pragma unroll
        for (int r = 0; r < 2; r++) {
            int d0 = w * 8 + r * 32;
            vv[r] = *(const u16x8*)&QKV[(rowbase + l) * (3 * CC) + 2 * CC + h * DD + d0];
        }
#pragma unroll
        for (int r = 0; r < 2; r++) {
            int row = w * 8 + r * 32 + krow;
            const char* src = (const char*)(QKV + (rowbase + row) * (3 * CC) + CC + h * DD) + kcolb;
            gload_lds16(src, &Ks[r * 2048 + w * 512]);
        }
#pragma unroll
        for (int r = 0; r < 2; r++) {
            int d0 = w * 8 + r * 32;
#pragma unroll
            for (int ii = 0; ii < 8; ii++)
                Vs[(d0 + ii) * 64 + (l ^ (ii << 3))] = vv[r][ii];
        }
        asm volatile("s_waitcnt vmcnt(0)" ::: "memory");
        __syncthreads();
    }

    const int ntiles = qbI + 1;
    int cur = 0;
    for (int t = 0; t < ntiles; t++) {
        const int kv0 = t * 64;
        const bool more = (t + 1 < ntiles);
        const int kbase = cur * 4096;

        // ---- issue next tile's loads (overlap with this tile's compute) ----
        u16x8 vn[2];
        if (more) {
            const int nkv0 = kv0 + 64;
#pragma unroll
            for (int r = 0; r < 2; r++) {
                int row = w * 8 + r * 32 + krow;
                const char* src = (const char*)(QKV + (rowbase + nkv0 + row) * (3 * CC) + CC + h * DD) + kcolb;
                gload_lds16(src, &Ks[(kbase ^ 4096) + r * 2048 + w * 512]);
            }
#pragma unroll
            for (int r = 0; r < 2; r++) {
                int d0 = w * 8 + r * 32;
                vn[r] = *(const u16x8*)&QKV[(rowbase + nkv0 + l) * (3 * CC) + 2 * CC + h * DD + d0];
            }
        }

        // ---- compute tile t from buffer cur ----
        f32x4 s[4];
#pragma unroll
        for (int n = 0; n < 4; n++) s[n] = fz;
        // S = Q K^T
#pragma unroll
        for (int ds = 0; ds < 2; ds++)
#pragma unroll
            for (int n = 0; n < 4; n++) {
                bf16x8 kb = *(const bf16x8*)&Ks[kbase + (n * 16 + c) * 64 + ((ds * 32 + g * 8) ^ ((c & 7) << 3))];
                s[n] = __builtin_amdgcn_mfma_f32_16x16x32_bf16(qa[ds], kb, s[n], 0, 0, 0);
            }

        const bool needmask = (kv0 + 63 > qrow0);
#pragma unroll
        for (int n = 0; n < 4; n++)
#pragma unroll
            for (int j = 0; j < 4; j++) {
                float v = s[n][j] * 0.125f;
                if (needmask) {
                    int row = qrow0 + g * 4 + j;
                    int col = kv0 + n * 16 + c;
                    if (col > row) v = -1e30f;
                }
                s[n][j] = v;
            }
        // online softmax (per row j, 16-lane-group reductions)
#pragma unroll
        for (int j = 0; j < 4; j++) {
            float m0 = fmaxf(fmaxf(s[0][j], s[1][j]), fmaxf(s[2][j], s[3][j]));
#pragma unroll
            for (int off = 1; off < 16; off <<= 1)
                m0 = fmaxf(m0, __shfl_xor(m0, off, 64));
            float mn = fmaxf(mrow[j], m0);
            float esc = __expf(mrow[j] - mn);
            mrow[j] = mn;
#pragma unroll
            for (int nd = 0; nd < 4; nd++) O[nd][j] *= esc;
            float rsum = 0.f;
#pragma unroll
            for (int n = 0; n < 4; n++) {
                float p = __expf(s[n][j] - mn);
                s[n][j] = p;
                rsum += p;
            }
#pragma unroll
            for (int off = 1; off < 16; off <<= 1)
                rsum += __shfl_xor(rsum, off, 64);
            lrow[j] = lrow[j] * esc + rsum;
        }
        // write P to per-wave swizzled LDS
#pragma unroll
        for (int n = 0; n < 4; n++)
#pragma unroll
            for (int j = 0; j < 4; j++) {
                int q = g * 4 + j;
                Ps[w * 1024 + q * 64 + ((n * 16 + c) ^ ((q & 7) << 3))] = f2bf(s[n][j]);
            }
        asm volatile("s_waitcnt lgkmcnt(0)" ::: "memory");
        // O += P V
#pragma unroll
        for (int ks = 0; ks < 2; ks++) {
            bf16x8 pa = *(const bf16x8*)&Ps[w * 1024 + c * 64 + ((ks * 32 + g * 8) ^ ((c & 7) << 3))];
#pragma unroll
            for (int nd = 0; nd < 4; nd++) {
                bf16x8 vb = *(const bf16x8*)&Vs[kbase + (nd * 16 + c) * 64 + ((ks * 32 + g * 8) ^ ((c & 7) << 3))];
                O[nd] = __builtin_amdgcn_mfma_f32_16x16x32_bf16(pa, vb, O[nd], 0, 0, 0);
            }
        }

        // ---- land next tile's V into other buffer ----
        if (more) {
#pragma unroll
            for (int r = 0; r < 2; r++) {
                int d0 = w * 8 + r * 32;
#pragma unroll
                for (int ii = 0; ii < 8; ii++)
                    Vs[(kbase ^ 4096) + (d0 + ii) * 64 + (l ^ (ii << 3))] = vn[r][ii];
            }
        }
        asm volatile("s_waitcnt vmcnt(0)" ::: "memory");
        __syncthreads();
        cur ^= 1;
    }

    // ---- epilogue: normalize, gate, write fp32 state + bf16 copy ----
    float gv = gates[depth];
    float sg = 1.f / (1.f + __expf(-gv));
    float inv[4];
#pragma unroll
    for (int j = 0; j < 4; j++) inv[j] = 1.f / lrow[j];
#pragma unroll
    for (int nd = 0; nd < 4; nd++)
#pragma unroll
        for (int j = 0; j < 4; j++) {
            float cur2 = O[nd][j] * inv[j];
            size_t idxo = (rowbase + qrow0 + g * 4 + j) * CC + h * DD + nd * 16 + c;
            float res;
            if (depth == 0) res = cur2;
            else res = sg * cur2 + (1.f - sg) * attF[idxo];
            if (depth < 2) attF[idxo] = res;  // depth-2 fp32 state is dead (final GEMM reads attB)
            attB[idxo] = f2bf(res);
        }
}

// ---------------- host ----------------
extern "C" void kernel_launch(void* const* d_in, const int* in_sizes, int n_in,
                              void* d_out, int out_size, void* d_ws, size_t ws_size,
                              hipStream_t stream) {
    const float* x      = (const float*)d_in[0];
    const float* W_attn = (const float*)d_in[1];
    const float* b_attn = (const float*)d_in[2];
    const float* W_proj = (const float*)d_in[3];
    const float* b_proj = (const float*)d_in[4];
    const float* gates  = (const float*)d_in[5];
    float* out = (float*)d_out;

    // ws layout (40 MiB):
    //   [0,8M)    Xb   [4096][1024] bf16  -- dead after QKV GEMM; reused as attB
    //   [8M,14M)  Wta  [3072][1024] bf16  (W_attn^T)
    //   [14M,16M) Wtp  [1024][1024] bf16  (W_proj^T)
    //   [16M,40M) QKV  [4096][3072] bf16
    // attF (fp32 gating state) aliases d_out (overwritten by final GEMM; never read-before-write).
    char* ws = (char*)d_ws;
    u16*   Xb   = (u16*)(ws);
    u16*   attB = (u16*)(ws);               // alias of Xb (Xb dead by then)
    u16*   Wta  = (u16*)(ws + 8388608);
    u16*   Wtp  = (u16*)(ws + 14680064);
    u16*   QKV  = (u16*)(ws + 16777216);
    float* attF = out;                      // alias of d_out
    (void)ws_size; (void)in_sizes; (void)n_in; (void)out_size;

    cvt_x<<<4096, 256, 0, stream>>>(x, Xb, 1048576);
    cvt_w_t<<<dim3(96, 32), 256, 0, stream>>>(W_attn, Wta, 1024, 3072);
    cvt_w_t<<<dim3(32, 32), 256, 0, stream>>>(W_proj, Wtp, 1024, 1024);

    // QKV projection: [4096,1024] x [1024,3072] -> bf16 [4096][3072]
    gemm_bf16<0><<<dim3(24, 32), 256, 0, stream>>>(Xb, Wta, b_attn, QKV, 1024, 3072);

    for (int depth = 0; depth < 3; depth++) {
        attn_kernel<<<dim3(32, 32), 256, 0, stream>>>(QKV, gates, attF, attB, depth);
        if (depth < 2) {
            // refinement: att_bf16 x W_attn[:, :2048]^T -> new q,k into QKV cols [0,2048)
            gemm_bf16<0><<<dim3(16, 32), 256, 0, stream>>>(attB, Wta, b_attn, QKV, 1024, 3072);
        }
    }
    // output projection -> fp32 d_out
    gemm_bf16<1><<<dim3(8, 32), 256, 0, stream>>>(attB, Wtp, b_proj, out, 1024, 1024);
}

// Round 6
// 385.598 us; speedup vs baseline: 1.7951x; 1.3068x over previous
//
#include <hip/hip_runtime.h>

typedef unsigned short u16;
typedef unsigned int u32;
typedef __bf16 bf16x8 __attribute__((ext_vector_type(8)));
typedef float f32x4 __attribute__((ext_vector_type(4)));
typedef u16 u16x8 __attribute__((ext_vector_type(8)));
typedef u16 u16x4 __attribute__((ext_vector_type(4)));

#define DEV static __device__ __forceinline__

// B=2, T=2048, C=1024, H=16, D=64, DEPTH=3
#define TT 2048
#define CC 1024
#define HH 16
#define DD 64

DEV u16 f2bf(float f) {
    u32 u = __float_as_uint(f);
    u += 0x7fffu + ((u >> 16) & 1u);
    return (u16)(u >> 16);
}

DEV void gload_lds16(const void* g, void* l) {
    __builtin_amdgcn_global_load_lds(
        (const __attribute__((address_space(1))) void*)g,
        (__attribute__((address_space(3))) void*)l,
        16, 0, 0);
}

// ---------------- converts ----------------
__global__ __launch_bounds__(256) void cvt_x(const float* __restrict__ x,
                                             u16* __restrict__ xb, int n4) {
    int i = blockIdx.x * 256 + threadIdx.x;
    if (i < n4) {
        float4 v = ((const float4*)x)[i];
        u16 o0 = f2bf(v.x), o1 = f2bf(v.y), o2 = f2bf(v.z), o3 = f2bf(v.w);
        u32 lo = (u32)o0 | ((u32)o1 << 16);
        u32 hi = (u32)o2 | ((u32)o3 << 16);
        ((u32*)xb)[i * 2]     = lo;
        ((u32*)xb)[i * 2 + 1] = hi;
    }
}

// W [K][N] fp32 -> Wt [N][K] bf16
__global__ __launch_bounds__(256) void cvt_w_t(const float* __restrict__ W,
                                               u16* __restrict__ Wt, int K, int N) {
    __shared__ float tile[32][33];
    int n0 = blockIdx.x * 32, k0 = blockIdx.y * 32;
    int tx = threadIdx.x & 31, ty = threadIdx.x >> 5;  // 32 x 8
#pragma unroll
    for (int i = 0; i < 4; i++)
        tile[ty + i * 8][tx] = W[(size_t)(k0 + ty + i * 8) * N + n0 + tx];
    __syncthreads();
#pragma unroll
    for (int i = 0; i < 4; i++) {
        int rr = ty + i * 8;
        Wt[(size_t)(n0 + rr) * K + k0 + tx] = f2bf(tile[tx][rr]);
    }
}

// ---------------- GEMM: C[M,N] = A[M,K](bf16) * Bt[N,K]^T(bf16) + bias ----------------
// 128x128 tile, BK=32, 4 waves, each wave 64x64 (4x4 frags of 16x16x32 MFMA)
template <int OUTF>
__global__ __launch_bounds__(256) void gemm_bf16(const u16* __restrict__ A,
                                                 const u16* __restrict__ Bt,
                                                 const float* __restrict__ bias,
                                                 void* __restrict__ Cout,
                                                 int K, int ldc) {
    __shared__ __align__(16) u16 As[4096];  // [128][32]
    __shared__ __align__(16) u16 Bs[4096];  // [128][32]

    const int tid = threadIdx.x;
    const int w = tid >> 6, l = tid & 63;
    const int wr = w >> 1, wc = w & 1;
    const int c = l & 15, g = l >> 4;
    const int rowB = blockIdx.y * 128;
    const int colB = blockIdx.x * 128;
    const int sr = l >> 2;          // staging row-in-quarter
    const int sk = (l & 3) * 8;     // staging k elem offset

    const f32x4 fz = {0.f, 0.f, 0.f, 0.f};
    f32x4 acc[4][4];
#pragma unroll
    for (int m = 0; m < 4; m++)
#pragma unroll
        for (int n = 0; n < 4; n++) acc[m][n] = fz;

    for (int k0 = 0; k0 < K; k0 += 32) {
#pragma unroll
        for (int i = 0; i < 2; i++) {
            int r = i * 64 + w * 16 + sr;
            gload_lds16(A + (size_t)(rowB + r) * K + k0 + sk, &As[i * 2048 + w * 512]);
            gload_lds16(Bt + (size_t)(colB + r) * K + k0 + sk, &Bs[i * 2048 + w * 512]);
        }
        asm volatile("s_waitcnt vmcnt(0)" ::: "memory");
        __syncthreads();

        bf16x8 af[4], bfr[4];
#pragma unroll
        for (int m = 0; m < 4; m++)
            af[m] = *(const bf16x8*)&As[(wr * 64 + m * 16 + c) * 32 + g * 8];
#pragma unroll
        for (int n = 0; n < 4; n++)
            bfr[n] = *(const bf16x8*)&Bs[(wc * 64 + n * 16 + c) * 32 + g * 8];
#pragma unroll
        for (int m = 0; m < 4; m++)
#pragma unroll
            for (int n = 0; n < 4; n++)
                acc[m][n] = __builtin_amdgcn_mfma_f32_16x16x32_bf16(af[m], bfr[n], acc[m][n], 0, 0, 0);
        __syncthreads();
    }

    const int orow = rowB + wr * 64;
    const int ocol = colB + wc * 64;
#pragma unroll
    for (int m = 0; m < 4; m++)
#pragma unroll
        for (int n = 0; n < 4; n++) {
            int col = ocol + n * 16 + c;
            float bv = bias[col];
#pragma unroll
            for (int j = 0; j < 4; j++) {
                int row = orow + m * 16 + g * 4 + j;
                float v = acc[m][n][j] + bv;
                if (OUTF)
                    ((float*)Cout)[(size_t)row * ldc + col] = v;
                else
                    ((u16*)Cout)[(size_t)row * ldc + col] = f2bf(v);
            }
        }
}

// ---------------- flash causal attention, one depth ----------------
// Swapped-operand scheme: S = mfma(K, Q) -> S[kv][q=c] lane-local per q-row;
// softmax = 15 local ops + 2 shfl; PV = mfma(V^T, P) -> O^T[d][q=c].
// Pair-balanced: block handles q-tiles (qp, 31-qp) sharing staged K/V tiles
// (uniform 33 tile-computes/block). 4 waves, wave owns 16 q-rows of each set.
// LDS: Ks[2][64][64] swz, Vs[2][64][64] (V^T) swz, Ps[4 waves][2 qsets][16][64] swz.
template <int NQ>
DEV void tile_step(const u16* __restrict__ Kb, const u16* __restrict__ Vb,
                   u16* __restrict__ Psw, const bf16x8 (*qa)[2], f32x4 (*O)[4],
                   float* mX, float* lX, const int* thr, const bool* nm,
                   int c, int g) {
    const f32x4 fz = {0.f, 0.f, 0.f, 0.f};
    const int swz = (c & 7) << 3;
    f32x4 s[NQ][4];
#pragma unroll
    for (int q = 0; q < NQ; q++)
#pragma unroll
        for (int m = 0; m < 4; m++) s[q][m] = fz;
    // S = K Q^T  (C layout: row=kv, col=q=c)
#pragma unroll
    for (int ds = 0; ds < 2; ds++)
#pragma unroll
        for (int m = 0; m < 4; m++) {
            bf16x8 kb = *(const bf16x8*)&Kb[(m * 16 + c) * 64 + ((ds * 32 + g * 8) ^ swz)];
#pragma unroll
            for (int q = 0; q < NQ; q++)
                s[q][m] = __builtin_amdgcn_mfma_f32_16x16x32_bf16(kb, qa[q][ds], s[q][m], 0, 0, 0);
        }
#pragma unroll
    for (int q = 0; q < NQ; q++) {
        float m0 = -1e30f;
        if (nm[q]) {
#pragma unroll
            for (int m = 0; m < 4; m++)
#pragma unroll
                for (int j = 0; j < 4; j++) {
                    int kvr = m * 16 + g * 4 + j;
                    float v = (kvr <= thr[q]) ? s[q][m][j] * 0.125f : -1e30f;
                    s[q][m][j] = v;
                    m0 = fmaxf(m0, v);
                }
        } else {
#pragma unroll
            for (int m = 0; m < 4; m++)
#pragma unroll
                for (int j = 0; j < 4; j++) {
                    float v = s[q][m][j] * 0.125f;
                    s[q][m][j] = v;
                    m0 = fmaxf(m0, v);
                }
        }
        m0 = fmaxf(m0, __shfl_xor(m0, 16, 64));
        m0 = fmaxf(m0, __shfl_xor(m0, 32, 64));
        float mn = fmaxf(mX[q], m0);
        float esc = __expf(mX[q] - mn);
        mX[q] = mn;
        float rsum = 0.f;
#pragma unroll
        for (int m = 0; m < 4; m++)
#pragma unroll
            for (int j = 0; j < 4; j++) {
                float p = __expf(s[q][m][j] - mn);
                s[q][m][j] = p;
                rsum += p;
            }
        rsum += __shfl_xor(rsum, 16, 64);
        rsum += __shfl_xor(rsum, 32, 64);
        lX[q] = lX[q] * esc + rsum;
#pragma unroll
        for (int nd = 0; nd < 4; nd++)
#pragma unroll
            for (int j = 0; j < 4; j++) O[q][nd][j] *= esc;
        // P write: Ps[q=c][kv], packed pairs (8 x ds_write_b32)
#pragma unroll
        for (int m = 0; m < 4; m++)
#pragma unroll
            for (int jj = 0; jj < 2; jj++) {
                u32 pw = (u32)f2bf(s[q][m][jj * 2]) | ((u32)f2bf(s[q][m][jj * 2 + 1]) << 16);
                int kvi = (m * 16 + g * 4 + jj * 2) ^ swz;
                *(u32*)&Psw[q * 1024 + c * 64 + kvi] = pw;
            }
    }
    asm volatile("s_waitcnt lgkmcnt(0)" ::: "memory");
    __builtin_amdgcn_sched_barrier(0);
    // O += V^T P^T  (C layout: row=d, col=q=c)
#pragma unroll
    for (int ks = 0; ks < 2; ks++) {
        bf16x8 pa[NQ];
#pragma unroll
        for (int q = 0; q < NQ; q++)
            pa[q] = *(const bf16x8*)&Psw[q * 1024 + c * 64 + ((ks * 32 + g * 8) ^ swz)];
#pragma unroll
        for (int nd = 0; nd < 4; nd++) {
            bf16x8 vb = *(const bf16x8*)&Vb[(nd * 16 + c) * 64 + ((ks * 32 + g * 8) ^ swz)];
#pragma unroll
            for (int q = 0; q < NQ; q++)
                O[q][nd] = __builtin_amdgcn_mfma_f32_16x16x32_bf16(vb, pa[q], O[q][nd], 0, 0, 0);
        }
    }
}

__global__ __launch_bounds__(256) void attn_kernel(const u16* __restrict__ QKV,  // [B*T][3C]
                                                   const float* __restrict__ gates,
                                                   float* __restrict__ attF,  // [B*T][C] fp32 state (= d_out)
                                                   u16* __restrict__ attB,    // [B*T][C] bf16 copy
                                                   int depth) {
    __shared__ __align__(16) u16 Ks[8192];  // 2 x 8KB
    __shared__ __align__(16) u16 Vs[8192];  // 2 x 8KB
    __shared__ __align__(16) u16 Ps[8192];  // 4 waves x 2 qsets x 2KB

    const int tid = threadIdx.x;
    const int w = tid >> 6, l = tid & 63;
    const int c = l & 15, g = l >> 4;

    // XCD-aware bijective remap: 512 blocks, each XCD owns 4 bh values
    const int f = blockIdx.y * 16 + blockIdx.x;
    const int xcd = f & 7;
    const int idx = f >> 3;                 // 0..63
    const int bh = xcd + 8 * (idx & 3);     // 0..31
    const int qp = idx >> 2;                // pair 0..15
    const int b = bh >> 4, h = bh & 15;
    const int qtB = 31 - qp;                // qset0 (always active)
    const int qtA = qp;                     // qset1 (active t <= qtA)
    const size_t rowbase = (size_t)b * TT;
    const int qrow0[2] = {qtB * 64 + w * 16, qtA * 64 + w * 16};
    const f32x4 fz = {0.f, 0.f, 0.f, 0.f};

    // staging constants
    const int krow = l >> 3;
    const int kcolb = (((l & 7) ^ krow) << 4);

    // Q fragments (B-operand layout): lane holds Q[q=qrow0+c][k=ds*32+g*8..]
    bf16x8 qa[2][2];
#pragma unroll
    for (int q = 0; q < 2; q++)
#pragma unroll
        for (int ds = 0; ds < 2; ds++)
            qa[q][ds] = *(const bf16x8*)&QKV[(rowbase + qrow0[q] + c) * (3 * CC) + h * DD + ds * 32 + g * 8];

    f32x4 O[2][4];
#pragma unroll
    for (int q = 0; q < 2; q++)
#pragma unroll
        for (int nd = 0; nd < 4; nd++) O[q][nd] = fz;
    float mX[2] = {-1e30f, -1e30f}, lX[2] = {0.f, 0.f};

    u16* Psw = &Ps[w * 2048];

    // ---- prologue: stage tile 0 into buffer 0 ----
    {
        u16x8 vv[2];
#pragma unroll
        for (int r = 0; r < 2; r++) {
            int d0 = w * 8 + r * 32;
            vv[r] = *(const u16x8*)&QKV[(rowbase + l) * (3 * CC) + 2 * CC + h * DD + d0];
        }
#pragma unroll
        for (int r = 0; r < 2; r++) {
            int row = w * 8 + r * 32 + krow;
            const char* src = (const char*)(QKV + (rowbase + row) * (3 * CC) + CC + h * DD) + kcolb;
            gload_lds16(src, &Ks[r * 2048 + w * 512]);
        }
#pragma unroll
        for (int r = 0; r < 2; r++) {
            int d0 = w * 8 + r * 32;
#pragma unroll
            for (int ii = 0; ii < 8; ii++)
                Vs[(d0 + ii) * 64 + (l ^ (ii << 3))] = vv[r][ii];
        }
        asm volatile("s_waitcnt vmcnt(0)" ::: "memory");
        __syncthreads();
    }

    const int ntB = qtB + 1;  // staged kv tiles
    int cur = 0;
    for (int t = 0; t < ntB; t++) {
        const int kv0 = t * 64;
        const bool more = (t + 1 < ntB);
        const int kbase = cur * 4096;

        // ---- issue next tile's loads (overlap with compute) ----
        u16x8 vn[2];
        if (more) {
            const int nkv0 = kv0 + 64;
#pragma unroll
            for (int r = 0; r < 2; r++) {
                int row = w * 8 + r * 32 + krow;
                const char* src = (const char*)(QKV + (rowbase + nkv0 + row) * (3 * CC) + CC + h * DD) + kcolb;
                gload_lds16(src, &Ks[(kbase ^ 4096) + r * 2048 + w * 512]);
            }
#pragma unroll
            for (int r = 0; r < 2; r++) {
                int d0 = w * 8 + r * 32;
                vn[r] = *(const u16x8*)&QKV[(rowbase + nkv0 + l) * (3 * CC) + 2 * CC + h * DD + d0];
            }
        }

        // ---- compute ----
        const int thr[2] = {qrow0[0] + c - kv0, qrow0[1] + c - kv0};
        const bool nm[2] = {t == qtB, t == qtA};
        if (t <= qtA)
            tile_step<2>(&Ks[kbase], &Vs[kbase], Psw, qa, O, mX, lX, thr, nm, c, g);
        else
            tile_step<1>(&Ks[kbase], &Vs[kbase], Psw, qa, O, mX, lX, thr, nm, c, g);

        // ---- land next tile's V into other buffer ----
        if (more) {
#pragma unroll
            for (int r = 0; r < 2; r++) {
                int d0 = w * 8 + r * 32;
#pragma unroll
                for (int ii = 0; ii < 8; ii++)
                    Vs[(kbase ^ 4096) + (d0 + ii) * 64 + (l ^ (ii << 3))] = vn[r][ii];
            }
        }
        asm volatile("s_waitcnt vmcnt(0)" ::: "memory");
        __syncthreads();
        cur ^= 1;
    }

    // ---- epilogue: normalize, gate, write (O^T layout: lane has q=c, d=nd*16+g*4+j) ----
    float gv = gates[depth];
    float sg = 1.f / (1.f + __expf(-gv));
#pragma unroll
    for (int q = 0; q < 2; q++) {
        float invl = 1.f / lX[q];
        size_t base = (rowbase + qrow0[q] + c) * CC + h * DD;
#pragma unroll
        for (int nd = 0; nd < 4; nd++) {
            int d = nd * 16 + g * 4;
            f32x4 res;
#pragma unroll
            for (int j = 0; j < 4; j++) res[j] = O[q][nd][j] * invl;
            if (depth > 0) {
                f32x4 prev = *(const f32x4*)&attF[base + d];
#pragma unroll
                for (int j = 0; j < 4; j++) res[j] = sg * res[j] + (1.f - sg) * prev[j];
            }
            if (depth < 2) *(f32x4*)&attF[base + d] = res;
            u16x4 rb;
#pragma unroll
            for (int j = 0; j < 4; j++) rb[j] = f2bf(res[j]);
            *(u16x4*)&attB[base + d] = rb;
        }
    }
}

// ---------------- host ----------------
extern "C" void kernel_launch(void* const* d_in, const int* in_sizes, int n_in,
                              void* d_out, int out_size, void* d_ws, size_t ws_size,
                              hipStream_t stream) {
    const float* x      = (const float*)d_in[0];
    const float* W_attn = (const float*)d_in[1];
    const float* b_attn = (const float*)d_in[2];
    const float* W_proj = (const float*)d_in[3];
    const float* b_proj = (const float*)d_in[4];
    const float* gates  = (const float*)d_in[5];
    float* out = (float*)d_out;

    // ws layout (40 MiB):
    //   [0,8M)    Xb   [4096][1024] bf16  -- dead after QKV GEMM; reused as attB
    //   [8M,14M)  Wta  [3072][1024] bf16  (W_attn^T)
    //   [14M,16M) Wtp  [1024][1024] bf16  (W_proj^T)
    //   [16M,40M) QKV  [4096][3072] bf16
    // attF (fp32 gating state) aliases d_out (overwritten by final GEMM; never read-before-write).
    char* ws = (char*)d_ws;
    u16*   Xb   = (u16*)(ws);
    u16*   attB = (u16*)(ws);               // alias of Xb (Xb dead by then)
    u16*   Wta  = (u16*)(ws + 8388608);
    u16*   Wtp  = (u16*)(ws + 14680064);
    u16*   QKV  = (u16*)(ws + 16777216);
    float* attF = out;                      // alias of d_out
    (void)ws_size; (void)in_sizes; (void)n_in; (void)out_size;

    cvt_x<<<4096, 256, 0, stream>>>(x, Xb, 1048576);
    cvt_w_t<<<dim3(96, 32), 256, 0, stream>>>(W_attn, Wta, 1024, 3072);
    cvt_w_t<<<dim3(32, 32), 256, 0, stream>>>(W_proj, Wtp, 1024, 1024);

    // QKV projection: [4096,1024] x [1024,3072] -> bf16 [4096][3072]
    gemm_bf16<0><<<dim3(24, 32), 256, 0, stream>>>(Xb, Wta, b_attn, QKV, 1024, 3072);

    for (int depth = 0; depth < 3; depth++) {
        attn_kernel<<<dim3(16, 32), 256, 0, stream>>>(QKV, gates, attF, attB, depth);
        if (depth < 2) {
            // refinement: att_bf16 x W_attn[:, :2048]^T -> new q,k into QKV cols [0,2048)
            gemm_bf16<0><<<dim3(16, 32), 256, 0, stream>>>(attB, Wta, b_attn, QKV, 1024, 3072);
        }
    }
    // output projection -> fp32 d_out
    gemm_bf16<1><<<dim3(8, 32), 256, 0, stream>>>(attB, Wtp, b_proj, out, 1024, 1024);
}